// Round 1
// baseline (511.688 us; speedup 1.0000x reference)
//
#include <hip/hip_runtime.h>
#include <hip/hip_bf16.h>

#define TOK   4096            // B*S
#define DDIM  1024
#define NEXP  8
#define HDIM  4096
#define KSEL  2
#define NPAIR (TOK * KSEL)    // 8192

typedef __attribute__((ext_vector_type(8))) _Float16 f16x8;
typedef __attribute__((ext_vector_type(4))) _Float16 f16x4;
typedef __attribute__((ext_vector_type(4))) float    f32x4;

__device__ __forceinline__ void gload16(const void* g, void* l) {
  __builtin_amdgcn_global_load_lds((const __attribute__((address_space(1))) void*)g,
                                   (__attribute__((address_space(3))) void*)l, 16, 0, 0);
}

__device__ __forceinline__ float gelu_tanh(float u) {
  float inner = 0.7978845608028654f * (u + 0.044715f * u * u * u);
  float t2 = __expf(2.f * inner);
  return u - u / (t2 + 1.f);     // == 0.5*u*(1+tanh(inner)), overflow-safe
}

// ---------------- router: one wave per token ----------------
__global__ __launch_bounds__(256) void k_router(const float* __restrict__ x,
    const float* __restrict__ rw, const float* __restrict__ rb,
    int* __restrict__ tidx, float* __restrict__ tw, int* __restrict__ counts) {
  const int t    = blockIdx.x * 4 + (threadIdx.x >> 6);
  const int lane = threadIdx.x & 63;
  const float* xr = x + (size_t)t * DDIM;
  float acc[NEXP];
#pragma unroll
  for (int e = 0; e < NEXP; ++e) acc[e] = 0.f;
  for (int d0 = lane * 4; d0 < DDIM; d0 += 256) {
    const float4 xv = *(const float4*)(xr + d0);
#pragma unroll
    for (int i = 0; i < 4; ++i) {
      const float xs = (&xv.x)[i];
      const float4 r0 = *(const float4*)(rw + (size_t)(d0 + i) * NEXP);
      const float4 r1 = *(const float4*)(rw + (size_t)(d0 + i) * NEXP + 4);
      acc[0] += xs * r0.x; acc[1] += xs * r0.y; acc[2] += xs * r0.z; acc[3] += xs * r0.w;
      acc[4] += xs * r1.x; acc[5] += xs * r1.y; acc[6] += xs * r1.z; acc[7] += xs * r1.w;
    }
  }
#pragma unroll
  for (int e = 0; e < NEXP; ++e) {
    float v = acc[e];
#pragma unroll
    for (int s = 32; s; s >>= 1) v += __shfl_xor(v, s, 64);
    acc[e] = v;
  }
  if (lane == 0) {
    float lg[NEXP];
#pragma unroll
    for (int e = 0; e < NEXP; ++e) lg[e] = acc[e] + rb[e];
    int i0 = 0;
#pragma unroll
    for (int e = 1; e < NEXP; ++e) if (lg[e] > lg[i0]) i0 = e;
    int i1 = -1; float best = -3.4e38f;
#pragma unroll
    for (int e = 0; e < NEXP; ++e) {
      if (e == i0) continue;
      if (lg[e] > best) { best = lg[e]; i1 = e; }
    }
    float w0 = 1.f / (1.f + expf(lg[i1] - lg[i0]));
    tidx[t * 2]     = i0;  tidx[t * 2 + 1] = i1;
    tw[t * 2]       = w0;  tw[t * 2 + 1]   = 1.f - w0;
    atomicAdd(&counts[i0], 1);
    atomicAdd(&counts[i1], 1);
  }
}

// ---------------- scan + scatter (single block) ----------------
__global__ void k_scan(const int* __restrict__ tidx, const float* __restrict__ tw,
                       const int* __restrict__ counts, int* __restrict__ offs,
                       int* __restrict__ row_token, float* __restrict__ row_w) {
  __shared__ int soff[NEXP + 1];
  __shared__ int scur[NEXP];
  if (threadIdx.x == 0) {
    int run = 0;
    for (int e = 0; e < NEXP; ++e) { soff[e] = run; run += counts[e]; }
    soff[NEXP] = run;
    for (int e = 0; e <= NEXP; ++e) offs[e] = soff[e];
  }
  __syncthreads();
  if (threadIdx.x < NEXP) scur[threadIdx.x] = soff[threadIdx.x];
  __syncthreads();
  for (int p = threadIdx.x; p < NPAIR; p += blockDim.x) {
    int e = tidx[p];
    int pos = atomicAdd(&scur[e], 1);
    row_token[pos] = p >> 1;
    row_w[pos]     = tw[p];
  }
}

// ---------------- x fp32 -> fp16 ----------------
__global__ __launch_bounds__(256) void k_cvt_x(const float* __restrict__ x,
                                               _Float16* __restrict__ xb) {
  size_t i = (size_t)(blockIdx.x * 256 + threadIdx.x) * 8;
  float4 a = *(const float4*)(x + i);
  float4 b = *(const float4*)(x + i + 4);
  f16x8 o;
  o[0] = (_Float16)a.x; o[1] = (_Float16)a.y; o[2] = (_Float16)a.z; o[3] = (_Float16)a.w;
  o[4] = (_Float16)b.x; o[5] = (_Float16)b.y; o[6] = (_Float16)b.z; o[7] = (_Float16)b.w;
  *(f16x8*)(xb + i) = o;
}

// ---------------- transpose fp32 [Rr][Cc] -> fp16 [Cc][Rr], per expert ----------------
__global__ __launch_bounds__(256) void k_transpose(const float* __restrict__ in,
    _Float16* __restrict__ out, int Rr, int Cc) {
  __shared__ _Float16 tile[64][72];
  const size_t esz = (size_t)Rr * Cc;
  const float* ip = in + esz * blockIdx.z;
  _Float16*    op = out + esz * blockIdx.z;
  const int i0 = blockIdx.y * 64;
  const int j0 = blockIdx.x * 64;
  const int tx = threadIdx.x & 15, ty = threadIdx.x >> 4;
#pragma unroll
  for (int rr = 0; rr < 4; ++rr) {
    int r = ty + rr * 16;
    float4 v = *(const float4*)(ip + (size_t)(i0 + r) * Cc + j0 + tx * 4);
    tile[r][tx * 4 + 0] = (_Float16)v.x;
    tile[r][tx * 4 + 1] = (_Float16)v.y;
    tile[r][tx * 4 + 2] = (_Float16)v.z;
    tile[r][tx * 4 + 3] = (_Float16)v.w;
  }
  __syncthreads();
#pragma unroll
  for (int cc = 0; cc < 4; ++cc) {
    int c = ty + cc * 16;
    f16x4 o;
#pragma unroll
    for (int k = 0; k < 4; ++k) o[k] = tile[tx * 4 + k][c];
    *(f16x4*)(op + (size_t)(j0 + c) * Rr + i0 + tx * 4) = o;
  }
}

// ---------------- GEMM1: h = gelu(X_gathered @ w1t^T + b1), fp16 out ----------------
#define BM 128
#define BN 128
#define BKK 64

__global__ __launch_bounds__(256) void k_gemm1(
    const _Float16* __restrict__ xb,    // [TOK][DDIM]
    const _Float16* __restrict__ w1t,   // [NEXP][HDIM][DDIM]
    const float* __restrict__ b1,       // [NEXP][HDIM]
    const int* __restrict__ offs,
    const int* __restrict__ row_token,
    _Float16* __restrict__ hbuf) {      // [NPAIR][HDIM]
  const int e    = blockIdx.z;
  const int off0 = offs[e];
  const int ne   = offs[e + 1] - off0;
  const int m0   = blockIdx.y * BM;
  if (m0 >= ne) return;
  const int n0   = blockIdx.x * BN;
  const int mrem = ne - m0;

  __shared__ __align__(16) _Float16 As[BM * BKK];  // swizzled, 16KB
  __shared__ __align__(16) _Float16 Bs[BN * BKK];  // 16KB

  const int tid = threadIdx.x;
  const int wv = tid >> 6, lane = tid & 63;
  const int sl = lane & 7, rsub = lane >> 3;
  const unsigned swzoff = (unsigned)((sl ^ rsub) * 16);   // row&7 == rsub for all issues

  const char* xb_c = (const char*)xb;
  const char* w1_c = (const char*)(w1t + (size_t)e * HDIM * DDIM);

  size_t abase[4], bbase[4];
#pragma unroll
  for (int i = 0; i < 4; ++i) {
    int r  = wv * 32 + i * 8 + rsub;
    int rr = (r < mrem) ? r : (mrem - 1);
    abase[i] = (size_t)row_token[off0 + m0 + rr] * (DDIM * 2);
    bbase[i] = (size_t)(n0 + r) * (DDIM * 2);
  }

  f32x4 acc[4][4] = {};
  const int wr = wv >> 1, wc = wv & 1;

  for (int ks = 0; ks < DDIM / BKK; ++ks) {
    const size_t kb = (size_t)ks * (BKK * 2);
#pragma unroll
    for (int i = 0; i < 4; ++i) {
      gload16(xb_c + abase[i] + kb + swzoff, (char*)As + (wv * 4 + i) * 1024);
      gload16(w1_c + bbase[i] + kb + swzoff, (char*)Bs + (wv * 4 + i) * 1024);
    }
    __syncthreads();
#pragma unroll
    for (int kk = 0; kk < 2; ++kk) {
      f16x8 af[4], bfr[4];
#pragma unroll
      for (int m = 0; m < 4; ++m) {
        int ar = wr * 64 + m * 16 + (lane & 15);
        int slot = kk * 4 + (lane >> 4);
        af[m] = *(const f16x8*)((const char*)As + ar * 128 + ((slot ^ (ar & 7)) * 16));
      }
#pragma unroll
      for (int n = 0; n < 4; ++n) {
        int br = wc * 64 + n * 16 + (lane & 15);
        int slot = kk * 4 + (lane >> 4);
        bfr[n] = *(const f16x8*)((const char*)Bs + br * 128 + ((slot ^ (br & 7)) * 16));
      }
#pragma unroll
      for (int m = 0; m < 4; ++m)
#pragma unroll
        for (int n = 0; n < 4; ++n)
          acc[m][n] = __builtin_amdgcn_mfma_f32_16x16x32_f16(af[m], bfr[n], acc[m][n], 0, 0, 0);
    }
    __syncthreads();
  }

  // epilogue: bias + gelu -> h (fp16)
  float bias[4];
#pragma unroll
  for (int n = 0; n < 4; ++n)
    bias[n] = b1[(size_t)e * HDIM + n0 + wc * 64 + n * 16 + (lane & 15)];
#pragma unroll
  for (int m = 0; m < 4; ++m) {
#pragma unroll
    for (int j = 0; j < 4; ++j) {
      int row = wr * 64 + m * 16 + (lane >> 4) * 4 + j;
      if (row < mrem) {
        _Float16* hr = hbuf + (size_t)(off0 + m0 + row) * HDIM + n0 + wc * 64 + (lane & 15);
#pragma unroll
        for (int n = 0; n < 4; ++n)
          hr[n * 16] = (_Float16)gelu_tanh(acc[m][n][j] + bias[n]);
      }
    }
  }
}

// ---------------- GEMM2: out += w * (H @ w2t^T + b2) ----------------
__global__ __launch_bounds__(256) void k_gemm2(
    const _Float16* __restrict__ hbuf,  // [NPAIR][HDIM]
    const _Float16* __restrict__ w2t,   // [NEXP][DDIM][HDIM]
    const float* __restrict__ b2,       // [NEXP][DDIM]
    const int* __restrict__ offs,
    const int* __restrict__ row_token,
    const float* __restrict__ row_w,
    float* __restrict__ out) {          // [TOK][DDIM]
  const int e    = blockIdx.z;
  const int off0 = offs[e];
  const int ne   = offs[e + 1] - off0;
  const int m0   = blockIdx.y * BM;
  if (m0 >= ne) return;
  const int n0   = blockIdx.x * BN;
  const int mrem = ne - m0;

  __shared__ __align__(16) _Float16 As[BM * BKK];
  __shared__ __align__(16) _Float16 Bs[BN * BKK];

  const int tid = threadIdx.x;
  const int wv = tid >> 6, lane = tid & 63;
  const int sl = lane & 7, rsub = lane >> 3;
  const unsigned swzoff = (unsigned)((sl ^ rsub) * 16);

  const char* h_c  = (const char*)hbuf;
  const char* w2_c = (const char*)(w2t + (size_t)e * DDIM * HDIM);

  size_t abase[4], bbase[4];
#pragma unroll
  for (int i = 0; i < 4; ++i) {
    int r  = wv * 32 + i * 8 + rsub;
    int rr = (r < mrem) ? r : (mrem - 1);
    abase[i] = (size_t)(off0 + m0 + rr) * (HDIM * 2);
    bbase[i] = (size_t)(n0 + r) * (HDIM * 2);
  }

  f32x4 acc[4][4] = {};
  const int wr = wv >> 1, wc = wv & 1;

  for (int ks = 0; ks < HDIM / BKK; ++ks) {
    const size_t kb = (size_t)ks * (BKK * 2);
#pragma unroll
    for (int i = 0; i < 4; ++i) {
      gload16(h_c  + abase[i] + kb + swzoff, (char*)As + (wv * 4 + i) * 1024);
      gload16(w2_c + bbase[i] + kb + swzoff, (char*)Bs + (wv * 4 + i) * 1024);
    }
    __syncthreads();
#pragma unroll
    for (int kk = 0; kk < 2; ++kk) {
      f16x8 af[4], bfr[4];
#pragma unroll
      for (int m = 0; m < 4; ++m) {
        int ar = wr * 64 + m * 16 + (lane & 15);
        int slot = kk * 4 + (lane >> 4);
        af[m] = *(const f16x8*)((const char*)As + ar * 128 + ((slot ^ (ar & 7)) * 16));
      }
#pragma unroll
      for (int n = 0; n < 4; ++n) {
        int br = wc * 64 + n * 16 + (lane & 15);
        int slot = kk * 4 + (lane >> 4);
        bfr[n] = *(const f16x8*)((const char*)Bs + br * 128 + ((slot ^ (br & 7)) * 16));
      }
#pragma unroll
      for (int m = 0; m < 4; ++m)
#pragma unroll
        for (int n = 0; n < 4; ++n)
          acc[m][n] = __builtin_amdgcn_mfma_f32_16x16x32_f16(af[m], bfr[n], acc[m][n], 0, 0, 0);
    }
    __syncthreads();
  }

  float bias[4];
#pragma unroll
  for (int n = 0; n < 4; ++n)
    bias[n] = b2[(size_t)e * DDIM + n0 + wc * 64 + n * 16 + (lane & 15)];
#pragma unroll
  for (int m = 0; m < 4; ++m) {
#pragma unroll
    for (int j = 0; j < 4; ++j) {
      int row = wr * 64 + m * 16 + (lane >> 4) * 4 + j;
      if (row < mrem) {
        int g = off0 + m0 + row;
        float wgt = row_w[g];
        float* op = out + (size_t)row_token[g] * DDIM + n0 + wc * 64 + (lane & 15);
#pragma unroll
        for (int n = 0; n < 4; ++n)
          atomicAdd(op + n * 16, wgt * (acc[m][n][j] + bias[n]));
      }
    }
  }
}

// ---------------- host ----------------
extern "C" void kernel_launch(void* const* d_in, const int* in_sizes, int n_in,
                              void* d_out, int out_size, void* d_ws, size_t ws_size,
                              hipStream_t stream) {
  const float* x  = (const float*)d_in[0];
  const float* rw = (const float*)d_in[1];
  const float* rb = (const float*)d_in[2];
  const float* w1 = (const float*)d_in[3];
  const float* b1 = (const float*)d_in[4];
  const float* w2 = (const float*)d_in[5];
  const float* b2 = (const float*)d_in[6];
  float* out = (float*)d_out;
  char* ws = (char*)d_ws;

  int*      tidx    = (int*)(ws + 0);              // 32KB
  float*    tw      = (float*)(ws + 32768);        // 32KB
  int*      counts  = (int*)(ws + 65536);
  int*      offs    = (int*)(ws + 65792);
  int*      row_tok = (int*)(ws + 66048);          // 32KB
  float*    row_w   = (float*)(ws + 98816);        // 32KB
  _Float16* xb      = (_Float16*)(ws + 131584);    // 8MB
  _Float16* wt      = (_Float16*)(ws + 8520192);   // 64MB (w1t then w2t)
  _Float16* hb      = (_Float16*)(ws + 75629056);  // 64MB

  hipMemsetAsync(counts, 0, NEXP * sizeof(int), stream);
  hipMemsetAsync(out, 0, (size_t)TOK * DDIM * sizeof(float), stream);

  k_router<<<dim3(TOK / 4), 256, 0, stream>>>(x, rw, rb, tidx, tw, counts);
  k_scan<<<dim3(1), 256, 0, stream>>>(tidx, tw, counts, offs, row_tok, row_w);
  k_cvt_x<<<dim3(TOK * DDIM / (256 * 8)), 256, 0, stream>>>(x, xb);
  k_transpose<<<dim3(HDIM / 64, DDIM / 64, NEXP), 256, 0, stream>>>(w1, wt, DDIM, HDIM);
  k_gemm1<<<dim3(HDIM / BN, TOK / BM, NEXP), 256, 0, stream>>>(xb, wt, b1, offs, row_tok, hb);
  k_transpose<<<dim3(DDIM / 64, HDIM / 64, NEXP), 256, 0, stream>>>(w2, wt, HDIM, DDIM);
  k_gemm2<<<dim3(DDIM / BN, TOK / BM, NEXP), 256, 0, stream>>>(hb, wt, b2, offs, row_tok, row_w, out);
}

// Round 2
// 492.183 us; speedup vs baseline: 1.0396x; 1.0396x over previous
//
#include <hip/hip_runtime.h>
#include <hip/hip_bf16.h>

#define TOK   4096            // B*S
#define DDIM  1024
#define NEXP  8
#define HDIM  4096
#define KSEL  2
#define NPAIR (TOK * KSEL)    // 8192

typedef __attribute__((ext_vector_type(8))) _Float16 f16x8;
typedef __attribute__((ext_vector_type(4))) _Float16 f16x4;
typedef __attribute__((ext_vector_type(4))) float    f32x4;

__device__ __forceinline__ void gload16(const void* g, void* l) {
  __builtin_amdgcn_global_load_lds((const __attribute__((address_space(1))) void*)g,
                                   (__attribute__((address_space(3))) void*)l, 16, 0, 0);
}

__device__ __forceinline__ float gelu_tanh(float u) {
  float inner = 0.7978845608028654f * (u + 0.044715f * u * u * u);
  float t2 = __expf(2.f * inner);
  return u - u / (t2 + 1.f);     // == 0.5*u*(1+tanh(inner)), overflow-safe
}

// ---------------- router: one wave per token ----------------
__global__ __launch_bounds__(256) void k_router(const float* __restrict__ x,
    const float* __restrict__ rw, const float* __restrict__ rb,
    int* __restrict__ tidx, float* __restrict__ tw, int* __restrict__ counts) {
  const int t    = blockIdx.x * 4 + (threadIdx.x >> 6);
  const int lane = threadIdx.x & 63;
  const float* xr = x + (size_t)t * DDIM;
  float acc[NEXP];
#pragma unroll
  for (int e = 0; e < NEXP; ++e) acc[e] = 0.f;
  for (int d0 = lane * 4; d0 < DDIM; d0 += 256) {
    const float4 xv = *(const float4*)(xr + d0);
#pragma unroll
    for (int i = 0; i < 4; ++i) {
      const float xs = (&xv.x)[i];
      const float4 r0 = *(const float4*)(rw + (size_t)(d0 + i) * NEXP);
      const float4 r1 = *(const float4*)(rw + (size_t)(d0 + i) * NEXP + 4);
      acc[0] += xs * r0.x; acc[1] += xs * r0.y; acc[2] += xs * r0.z; acc[3] += xs * r0.w;
      acc[4] += xs * r1.x; acc[5] += xs * r1.y; acc[6] += xs * r1.z; acc[7] += xs * r1.w;
    }
  }
#pragma unroll
  for (int e = 0; e < NEXP; ++e) {
    float v = acc[e];
#pragma unroll
    for (int s = 32; s; s >>= 1) v += __shfl_xor(v, s, 64);
    acc[e] = v;
  }
  if (lane == 0) {
    float lg[NEXP];
#pragma unroll
    for (int e = 0; e < NEXP; ++e) lg[e] = acc[e] + rb[e];
    int i0 = 0;
#pragma unroll
    for (int e = 1; e < NEXP; ++e) if (lg[e] > lg[i0]) i0 = e;
    int i1 = -1; float best = -3.4e38f;
#pragma unroll
    for (int e = 0; e < NEXP; ++e) {
      if (e == i0) continue;
      if (lg[e] > best) { best = lg[e]; i1 = e; }
    }
    float w0 = 1.f / (1.f + expf(lg[i1] - lg[i0]));
    tidx[t * 2]     = i0;  tidx[t * 2 + 1] = i1;
    tw[t * 2]       = w0;  tw[t * 2 + 1]   = 1.f - w0;
    atomicAdd(&counts[i0], 1);
    atomicAdd(&counts[i1], 1);
  }
}

// ---------------- scan + scatter (single block, ballot-aggregated) ----------------
__global__ __launch_bounds__(1024) void k_scan(const int* __restrict__ tidx,
                       const float* __restrict__ tw,
                       const int* __restrict__ counts, int* __restrict__ offs,
                       int* __restrict__ row_token, float* __restrict__ row_w) {
  __shared__ int soff[NEXP + 1];
  __shared__ int scur[NEXP];
  if (threadIdx.x == 0) {
    int run = 0;
    for (int e = 0; e < NEXP; ++e) { soff[e] = run; run += counts[e]; }
    soff[NEXP] = run;
    for (int e = 0; e <= NEXP; ++e) offs[e] = soff[e];
  }
  __syncthreads();
  if (threadIdx.x < NEXP) scur[threadIdx.x] = soff[threadIdx.x];
  __syncthreads();
  const int lane = threadIdx.x & 63;
#pragma unroll
  for (int it = 0; it < NPAIR / 1024; ++it) {
    const int p = it * 1024 + threadIdx.x;
    const int e = tidx[p];
    int pos = 0;
#pragma unroll
    for (int ee = 0; ee < NEXP; ++ee) {
      unsigned long long m = __ballot(e == ee);
      if (!m) continue;
      int base = 0;
      if (lane == 0) base = atomicAdd(&scur[ee], __popcll(m));
      base = __shfl(base, 0, 64);
      if (e == ee) pos = base + __popcll(m & ((1ull << lane) - 1ull));
    }
    row_token[pos] = p >> 1;
    row_w[pos]     = tw[p];
  }
}

// ---------------- x fp32 -> fp16 ----------------
__global__ __launch_bounds__(256) void k_cvt_x(const float* __restrict__ x,
                                               _Float16* __restrict__ xb) {
  size_t i = (size_t)(blockIdx.x * 256 + threadIdx.x) * 8;
  float4 a = *(const float4*)(x + i);
  float4 b = *(const float4*)(x + i + 4);
  f16x8 o;
  o[0] = (_Float16)a.x; o[1] = (_Float16)a.y; o[2] = (_Float16)a.z; o[3] = (_Float16)a.w;
  o[4] = (_Float16)b.x; o[5] = (_Float16)b.y; o[6] = (_Float16)b.z; o[7] = (_Float16)b.w;
  *(f16x8*)(xb + i) = o;
}

// ---------------- transpose fp32 [Rr][Cc] -> fp16 [Cc][Rr], per expert ----------------
__global__ __launch_bounds__(256) void k_transpose(const float* __restrict__ in,
    _Float16* __restrict__ out, int Rr, int Cc) {
  __shared__ _Float16 tile[64][72];
  const size_t esz = (size_t)Rr * Cc;
  const float* ip = in + esz * blockIdx.z;
  _Float16*    op = out + esz * blockIdx.z;
  const int i0 = blockIdx.y * 64;
  const int j0 = blockIdx.x * 64;
  const int tx = threadIdx.x & 15, ty = threadIdx.x >> 4;
#pragma unroll
  for (int rr = 0; rr < 4; ++rr) {
    int r = ty + rr * 16;
    float4 v = *(const float4*)(ip + (size_t)(i0 + r) * Cc + j0 + tx * 4);
    tile[r][tx * 4 + 0] = (_Float16)v.x;
    tile[r][tx * 4 + 1] = (_Float16)v.y;
    tile[r][tx * 4 + 2] = (_Float16)v.z;
    tile[r][tx * 4 + 3] = (_Float16)v.w;
  }
  __syncthreads();
#pragma unroll
  for (int cc = 0; cc < 4; ++cc) {
    int c = ty + cc * 16;
    f16x4 o;
#pragma unroll
    for (int k = 0; k < 4; ++k) o[k] = tile[tx * 4 + k][c];
    *(f16x4*)(op + (size_t)(j0 + c) * Rr + i0 + tx * 4) = o;
  }
}

// ---------------- GEMM1: h = gelu(X_gathered @ w1t^T + b1), fp16 out ----------------
#define BM 128
#define BN 128
#define BKK 64

__global__ __launch_bounds__(256) void k_gemm1(
    const _Float16* __restrict__ xb,    // [TOK][DDIM]
    const _Float16* __restrict__ w1t,   // [NEXP][HDIM][DDIM]
    const float* __restrict__ b1,       // [NEXP][HDIM]
    const int* __restrict__ offs,
    const int* __restrict__ row_token,
    _Float16* __restrict__ hbuf) {      // [NPAIR][HDIM]
  const int e    = blockIdx.z;
  const int off0 = offs[e];
  const int ne   = offs[e + 1] - off0;
  const int m0   = blockIdx.y * BM;
  if (m0 >= ne) return;
  const int n0   = blockIdx.x * BN;
  const int mrem = ne - m0;

  __shared__ __align__(16) char smem[32768];        // As(16K) + Bs(16K); reused for C restage
  _Float16* As = (_Float16*)smem;
  _Float16* Bs = (_Float16*)(smem + 16384);

  const int tid = threadIdx.x;
  const int wv = tid >> 6, lane = tid & 63;
  const int sl = lane & 7, rsub = lane >> 3;
  const unsigned swzoff = (unsigned)((sl ^ rsub) * 16);   // row&7 == rsub for all issues

  const char* xb_c = (const char*)xb;
  const char* w1_c = (const char*)(w1t + (size_t)e * HDIM * DDIM);

  size_t abase[4], bbase[4];
#pragma unroll
  for (int i = 0; i < 4; ++i) {
    int r  = wv * 32 + i * 8 + rsub;
    int rr = (r < mrem) ? r : (mrem - 1);
    abase[i] = (size_t)row_token[off0 + m0 + rr] * (DDIM * 2);
    bbase[i] = (size_t)(n0 + r) * (DDIM * 2);
  }

  f32x4 acc[4][4] = {};
  const int wr = wv >> 1, wc = wv & 1;

  for (int ks = 0; ks < DDIM / BKK; ++ks) {
    const size_t kb = (size_t)ks * (BKK * 2);
#pragma unroll
    for (int i = 0; i < 4; ++i) {
      gload16(xb_c + abase[i] + kb + swzoff, (char*)As + (wv * 4 + i) * 1024);
      gload16(w1_c + bbase[i] + kb + swzoff, (char*)Bs + (wv * 4 + i) * 1024);
    }
    __syncthreads();
#pragma unroll
    for (int kk = 0; kk < 2; ++kk) {
      f16x8 af[4], bfr[4];
#pragma unroll
      for (int m = 0; m < 4; ++m) {
        int ar = wr * 64 + m * 16 + (lane & 15);
        int slot = kk * 4 + (lane >> 4);
        af[m] = *(const f16x8*)((const char*)As + ar * 128 + ((slot ^ (ar & 7)) * 16));
      }
#pragma unroll
      for (int n = 0; n < 4; ++n) {
        int br = wc * 64 + n * 16 + (lane & 15);
        int slot = kk * 4 + (lane >> 4);
        bfr[n] = *(const f16x8*)((const char*)Bs + br * 128 + ((slot ^ (br & 7)) * 16));
      }
#pragma unroll
      for (int m = 0; m < 4; ++m)
#pragma unroll
        for (int n = 0; n < 4; ++n)
          acc[m][n] = __builtin_amdgcn_mfma_f32_16x16x32_f16(af[m], bfr[n], acc[m][n], 0, 0, 0);
    }
    __syncthreads();
  }

  // epilogue: bias + gelu -> restage f16 C-tile in LDS (16B-slot XOR swizzle) -> coalesced stores
  float bias[4];
#pragma unroll
  for (int n = 0; n < 4; ++n)
    bias[n] = b1[(size_t)e * HDIM + n0 + wc * 64 + n * 16 + (lane & 15)];
#pragma unroll
  for (int m = 0; m < 4; ++m) {
#pragma unroll
    for (int j = 0; j < 4; ++j) {
      int row = wr * 64 + m * 16 + (lane >> 4) * 4 + j;
#pragma unroll
      for (int n = 0; n < 4; ++n) {
        int col = wc * 64 + n * 16 + (lane & 15);
        *(_Float16*)(smem + (row << 8) + (((col << 1) ^ ((row & 15) << 4)))) =
            (_Float16)gelu_tanh(acc[m][n][j] + bias[n]);
      }
    }
  }
  __syncthreads();
  {
    const int srow = tid >> 1, half = tid & 1;
    if (srow < mrem) {
      _Float16* hr = hbuf + (size_t)(off0 + m0 + srow) * HDIM + n0 + half * 64;
#pragma unroll
      for (int i = 0; i < 8; ++i) {
        f16x8 v = *(const f16x8*)(smem + (srow << 8) + (((half * 128 + i * 16) ^ ((srow & 15) << 4))));
        *(f16x8*)(hr + i * 8) = v;
      }
    }
  }
}

// ---------------- GEMM2 (split-K=2): out += w * (H @ w2t^T + b2) ----------------
__global__ __launch_bounds__(256) void k_gemm2(
    const _Float16* __restrict__ hbuf,  // [NPAIR][HDIM]
    const _Float16* __restrict__ w2t,   // [NEXP][DDIM][HDIM]
    const float* __restrict__ b2,       // [NEXP][DDIM]
    const int* __restrict__ offs,
    const int* __restrict__ row_token,
    const float* __restrict__ row_w,
    float* __restrict__ out) {          // [TOK][DDIM]
  const int e    = blockIdx.z >> 1;
  const int kh   = blockIdx.z & 1;     // split-K half
  const int off0 = offs[e];
  const int ne   = offs[e + 1] - off0;
  const int m0   = blockIdx.y * BM;
  if (m0 >= ne) return;
  const int n0   = blockIdx.x * BN;
  const int mrem = ne - m0;

  __shared__ __align__(16) _Float16 As[BM * BKK];
  __shared__ __align__(16) _Float16 Bs[BN * BKK];

  const int tid = threadIdx.x;
  const int wv = tid >> 6, lane = tid & 63;
  const int sl = lane & 7, rsub = lane >> 3;
  const unsigned swzoff = (unsigned)((sl ^ rsub) * 16);

  const char* h_c  = (const char*)hbuf;
  const char* w2_c = (const char*)(w2t + (size_t)e * DDIM * HDIM);

  size_t abase[4], bbase[4];
#pragma unroll
  for (int i = 0; i < 4; ++i) {
    int r  = wv * 32 + i * 8 + rsub;
    int rr = (r < mrem) ? r : (mrem - 1);
    abase[i] = (size_t)(off0 + m0 + rr) * (HDIM * 2);
    bbase[i] = (size_t)(n0 + r) * (HDIM * 2);
  }

  f32x4 acc[4][4] = {};
  const int wr = wv >> 1, wc = wv & 1;

  for (int ks = 0; ks < 32; ++ks) {                       // K half = 2048
    const size_t kb = (size_t)(kh * 32 + ks) * (BKK * 2);
#pragma unroll
    for (int i = 0; i < 4; ++i) {
      gload16(h_c  + abase[i] + kb + swzoff, (char*)As + (wv * 4 + i) * 1024);
      gload16(w2_c + bbase[i] + kb + swzoff, (char*)Bs + (wv * 4 + i) * 1024);
    }
    __syncthreads();
#pragma unroll
    for (int kk = 0; kk < 2; ++kk) {
      f16x8 af[4], bfr[4];
#pragma unroll
      for (int m = 0; m < 4; ++m) {
        int ar = wr * 64 + m * 16 + (lane & 15);
        int slot = kk * 4 + (lane >> 4);
        af[m] = *(const f16x8*)((const char*)As + ar * 128 + ((slot ^ (ar & 7)) * 16));
      }
#pragma unroll
      for (int n = 0; n < 4; ++n) {
        int br = wc * 64 + n * 16 + (lane & 15);
        int slot = kk * 4 + (lane >> 4);
        bfr[n] = *(const f16x8*)((const char*)Bs + br * 128 + ((slot ^ (br & 7)) * 16));
      }
#pragma unroll
      for (int m = 0; m < 4; ++m)
#pragma unroll
        for (int n = 0; n < 4; ++n)
          acc[m][n] = __builtin_amdgcn_mfma_f32_16x16x32_f16(af[m], bfr[n], acc[m][n], 0, 0, 0);
    }
    __syncthreads();
  }

  float bias[4];
#pragma unroll
  for (int n = 0; n < 4; ++n)
    bias[n] = (kh == 0) ? b2[(size_t)e * DDIM + n0 + wc * 64 + n * 16 + (lane & 15)] : 0.f;
#pragma unroll
  for (int m = 0; m < 4; ++m) {
#pragma unroll
    for (int j = 0; j < 4; ++j) {
      int row = wr * 64 + m * 16 + (lane >> 4) * 4 + j;
      if (row < mrem) {
        int g = off0 + m0 + row;
        float wgt = row_w[g];
        float* op = out + (size_t)row_token[g] * DDIM + n0 + wc * 64 + (lane & 15);
#pragma unroll
        for (int n = 0; n < 4; ++n)
          atomicAdd(op + n * 16, wgt * (acc[m][n][j] + bias[n]));
      }
    }
  }
}

// ---------------- host ----------------
extern "C" void kernel_launch(void* const* d_in, const int* in_sizes, int n_in,
                              void* d_out, int out_size, void* d_ws, size_t ws_size,
                              hipStream_t stream) {
  const float* x  = (const float*)d_in[0];
  const float* rw = (const float*)d_in[1];
  const float* rb = (const float*)d_in[2];
  const float* w1 = (const float*)d_in[3];
  const float* b1 = (const float*)d_in[4];
  const float* w2 = (const float*)d_in[5];
  const float* b2 = (const float*)d_in[6];
  float* out = (float*)d_out;
  char* ws = (char*)d_ws;

  int*      tidx    = (int*)(ws + 0);              // 32KB
  float*    tw      = (float*)(ws + 32768);        // 32KB
  int*      counts  = (int*)(ws + 65536);
  int*      offs    = (int*)(ws + 65792);
  int*      row_tok = (int*)(ws + 66048);          // 32KB
  float*    row_w   = (float*)(ws + 98816);        // 32KB
  _Float16* xb      = (_Float16*)(ws + 131584);    // 8MB
  _Float16* wt      = (_Float16*)(ws + 8520192);   // 64MB (w1t then w2t)
  _Float16* hb      = (_Float16*)(ws + 75629056);  // 64MB

  hipMemsetAsync(counts, 0, NEXP * sizeof(int), stream);
  hipMemsetAsync(out, 0, (size_t)TOK * DDIM * sizeof(float), stream);

  k_router<<<dim3(TOK / 4), 256, 0, stream>>>(x, rw, rb, tidx, tw, counts);
  k_scan<<<dim3(1), 1024, 0, stream>>>(tidx, tw, counts, offs, row_tok, row_w);
  k_cvt_x<<<dim3(TOK * DDIM / (256 * 8)), 256, 0, stream>>>(x, xb);
  k_transpose<<<dim3(HDIM / 64, DDIM / 64, NEXP), 256, 0, stream>>>(w1, wt, DDIM, HDIM);
  k_gemm1<<<dim3(HDIM / BN, TOK / BM, NEXP), 256, 0, stream>>>(xb, wt, b1, offs, row_tok, hb);
  k_transpose<<<dim3(DDIM / 64, HDIM / 64, NEXP), 256, 0, stream>>>(w2, wt, HDIM, DDIM);
  k_gemm2<<<dim3(DDIM / BN, TOK / BM, NEXP * 2), 256, 0, stream>>>(hb, wt, b2, offs, row_tok, row_w, out);
}

// Round 3
// 437.310 us; speedup vs baseline: 1.1701x; 1.1255x over previous
//
#include <hip/hip_runtime.h>
#include <hip/hip_bf16.h>

#define TOK   4096            // B*S
#define DDIM  1024
#define NEXP  8
#define HDIM  4096
#define KSEL  2
#define NPAIR (TOK * KSEL)    // 8192

typedef __attribute__((ext_vector_type(8))) _Float16 f16x8;
typedef __attribute__((ext_vector_type(4))) _Float16 f16x4;
typedef __attribute__((ext_vector_type(4))) float    f32x4;

__device__ __forceinline__ void gload16(const void* g, void* l) {
  __builtin_amdgcn_global_load_lds((const __attribute__((address_space(1))) void*)g,
                                   (__attribute__((address_space(3))) void*)l, 16, 0, 0);
}

__device__ __forceinline__ float gelu_tanh(float u) {
  float inner = 0.7978845608028654f * (u + 0.044715f * u * u * u);
  float t2 = __expf(2.f * inner);
  return u - u / (t2 + 1.f);     // == 0.5*u*(1+tanh(inner)), overflow-safe
}

// ---------------- router: one wave per token ----------------
__global__ __launch_bounds__(256) void k_router(const float* __restrict__ x,
    const float* __restrict__ rw, const float* __restrict__ rb,
    int* __restrict__ tidx, float* __restrict__ tw, int* __restrict__ counts) {
  const int t    = blockIdx.x * 4 + (threadIdx.x >> 6);
  const int lane = threadIdx.x & 63;
  const float* xr = x + (size_t)t * DDIM;
  float acc[NEXP];
#pragma unroll
  for (int e = 0; e < NEXP; ++e) acc[e] = 0.f;
  for (int d0 = lane * 4; d0 < DDIM; d0 += 256) {
    const float4 xv = *(const float4*)(xr + d0);
#pragma unroll
    for (int i = 0; i < 4; ++i) {
      const float xs = (&xv.x)[i];
      const float4 r0 = *(const float4*)(rw + (size_t)(d0 + i) * NEXP);
      const float4 r1 = *(const float4*)(rw + (size_t)(d0 + i) * NEXP + 4);
      acc[0] += xs * r0.x; acc[1] += xs * r0.y; acc[2] += xs * r0.z; acc[3] += xs * r0.w;
      acc[4] += xs * r1.x; acc[5] += xs * r1.y; acc[6] += xs * r1.z; acc[7] += xs * r1.w;
    }
  }
#pragma unroll
  for (int e = 0; e < NEXP; ++e) {
    float v = acc[e];
#pragma unroll
    for (int s = 32; s; s >>= 1) v += __shfl_xor(v, s, 64);
    acc[e] = v;
  }
  if (lane == 0) {
    float lg[NEXP];
#pragma unroll
    for (int e = 0; e < NEXP; ++e) lg[e] = acc[e] + rb[e];
    int i0 = 0;
#pragma unroll
    for (int e = 1; e < NEXP; ++e) if (lg[e] > lg[i0]) i0 = e;
    int i1 = -1; float best = -3.4e38f;
#pragma unroll
    for (int e = 0; e < NEXP; ++e) {
      if (e == i0) continue;
      if (lg[e] > best) { best = lg[e]; i1 = e; }
    }
    float w0 = 1.f / (1.f + expf(lg[i1] - lg[i0]));
    tidx[t * 2]     = i0;  tidx[t * 2 + 1] = i1;
    tw[t * 2]       = w0;  tw[t * 2 + 1]   = 1.f - w0;
    atomicAdd(&counts[i0], 1);
    atomicAdd(&counts[i1], 1);
  }
}

// ---------------- scan + scatter (single block, ballot-aggregated) ----------------
__global__ __launch_bounds__(1024) void k_scan(const int* __restrict__ tidx,
                       const float* __restrict__ tw,
                       const int* __restrict__ counts, int* __restrict__ offs,
                       int* __restrict__ row_token, float* __restrict__ row_w,
                       int* __restrict__ inv) {
  __shared__ int soff[NEXP + 1];
  __shared__ int scur[NEXP];
  if (threadIdx.x == 0) {
    int run = 0;
    for (int e = 0; e < NEXP; ++e) { soff[e] = run; run += counts[e]; }
    soff[NEXP] = run;
    for (int e = 0; e <= NEXP; ++e) offs[e] = soff[e];
  }
  __syncthreads();
  if (threadIdx.x < NEXP) scur[threadIdx.x] = soff[threadIdx.x];
  __syncthreads();
  const int lane = threadIdx.x & 63;
#pragma unroll
  for (int it = 0; it < NPAIR / 1024; ++it) {
    const int p = it * 1024 + threadIdx.x;
    const int e = tidx[p];
    int pos = 0;
#pragma unroll
    for (int ee = 0; ee < NEXP; ++ee) {
      unsigned long long m = __ballot(e == ee);
      if (!m) continue;
      int base = 0;
      if (lane == 0) base = atomicAdd(&scur[ee], __popcll(m));
      base = __shfl(base, 0, 64);
      if (e == ee) pos = base + __popcll(m & ((1ull << lane) - 1ull));
    }
    row_token[pos] = p >> 1;
    row_w[pos]     = tw[p];
    inv[p]         = pos;
  }
}

// ---------------- x fp32 -> fp16 ----------------
__global__ __launch_bounds__(256) void k_cvt_x(const float* __restrict__ x,
                                               _Float16* __restrict__ xb) {
  size_t i = (size_t)(blockIdx.x * 256 + threadIdx.x) * 8;
  float4 a = *(const float4*)(x + i);
  float4 b = *(const float4*)(x + i + 4);
  f16x8 o;
  o[0] = (_Float16)a.x; o[1] = (_Float16)a.y; o[2] = (_Float16)a.z; o[3] = (_Float16)a.w;
  o[4] = (_Float16)b.x; o[5] = (_Float16)b.y; o[6] = (_Float16)b.z; o[7] = (_Float16)b.w;
  *(f16x8*)(xb + i) = o;
}

// ---------------- transpose fp32 [Rr][Cc] -> fp16 [Cc][Rr], per expert ----------------
__global__ __launch_bounds__(256) void k_transpose(const float* __restrict__ in,
    _Float16* __restrict__ out, int Rr, int Cc) {
  __shared__ _Float16 tile[64][72];
  const size_t esz = (size_t)Rr * Cc;
  const float* ip = in + esz * blockIdx.z;
  _Float16*    op = out + esz * blockIdx.z;
  const int i0 = blockIdx.y * 64;
  const int j0 = blockIdx.x * 64;
  const int tx = threadIdx.x & 15, ty = threadIdx.x >> 4;
#pragma unroll
  for (int rr = 0; rr < 4; ++rr) {
    int r = ty + rr * 16;
    float4 v = *(const float4*)(ip + (size_t)(i0 + r) * Cc + j0 + tx * 4);
    tile[r][tx * 4 + 0] = (_Float16)v.x;
    tile[r][tx * 4 + 1] = (_Float16)v.y;
    tile[r][tx * 4 + 2] = (_Float16)v.z;
    tile[r][tx * 4 + 3] = (_Float16)v.w;
  }
  __syncthreads();
#pragma unroll
  for (int cc = 0; cc < 4; ++cc) {
    int c = ty + cc * 16;
    f16x4 o;
#pragma unroll
    for (int k = 0; k < 4; ++k) o[k] = tile[tx * 4 + k][c];
    *(f16x4*)(op + (size_t)(j0 + c) * Rr + i0 + tx * 4) = o;
  }
}

#define BM 128
#define BN 128
#define BKK 64

// ---------------- GEMM1: h = gelu(X_gathered @ w1t^T + b1), fp16 out ----------------
// double-buffered LDS, raw barriers, counted vmcnt (prefetch stays in flight)
__global__ __launch_bounds__(256) void k_gemm1(
    const _Float16* __restrict__ xb,    // [TOK][DDIM]
    const _Float16* __restrict__ w1t,   // [NEXP][HDIM][DDIM]
    const float* __restrict__ b1,       // [NEXP][HDIM]
    const int* __restrict__ offs,
    const int* __restrict__ row_token,
    _Float16* __restrict__ hbuf) {      // [NPAIR][HDIM]
  const int e    = blockIdx.z;
  const int off0 = offs[e];
  const int ne   = offs[e + 1] - off0;
  const int m0   = blockIdx.y * BM;
  if (m0 >= ne) return;
  const int n0   = blockIdx.x * BN;
  const int mrem = ne - m0;

  __shared__ __align__(16) char smem[65536];  // A0 A1 | B0 B1 (16KB each)

  const int tid = threadIdx.x;
  const int wv = tid >> 6, lane = tid & 63;
  const int sl = lane & 7, rsub = lane >> 3;
  const unsigned swzoff = (unsigned)((sl ^ rsub) * 16);

  const char* a_c = (const char*)xb;
  const char* b_c = (const char*)(w1t + (size_t)e * HDIM * DDIM);

  size_t abase[4], bbase[4];
#pragma unroll
  for (int i = 0; i < 4; ++i) {
    int r  = wv * 32 + i * 8 + rsub;
    int rr = (r < mrem) ? r : (mrem - 1);
    abase[i] = (size_t)row_token[off0 + m0 + rr] * (DDIM * 2);
    bbase[i] = (size_t)(n0 + r) * (DDIM * 2);
  }

  f32x4 acc[4][4] = {};
  const int wr = wv >> 1, wc = wv & 1;
  const int NT = DDIM / BKK;   // 16

  // prologue: stage tile 0 into buffer 0
#pragma unroll
  for (int i = 0; i < 4; ++i) {
    gload16(a_c + abase[i] + swzoff, smem + (wv * 4 + i) * 1024);
    gload16(b_c + bbase[i] + swzoff, smem + 32768 + (wv * 4 + i) * 1024);
  }

  for (int ks = 0; ks < NT; ++ks) {
    const int cur = ks & 1;
    if (ks + 1 < NT) {
      const int nxt = cur ^ 1;
      const size_t kb = (size_t)(ks + 1) * (BKK * 2);
#pragma unroll
      for (int i = 0; i < 4; ++i) {
        gload16(a_c + abase[i] + kb + swzoff, smem + nxt * 16384 + (wv * 4 + i) * 1024);
        gload16(b_c + bbase[i] + kb + swzoff, smem + 32768 + nxt * 16384 + (wv * 4 + i) * 1024);
      }
      asm volatile("s_waitcnt vmcnt(8)" ::: "memory");
    } else {
      asm volatile("s_waitcnt vmcnt(0)" ::: "memory");
    }
    __builtin_amdgcn_sched_barrier(0);
    __builtin_amdgcn_s_barrier();
    const char* Ab = smem + cur * 16384;
    const char* Bb = smem + 32768 + cur * 16384;
#pragma unroll
    for (int kk = 0; kk < 2; ++kk) {
      f16x8 af[4], bfr[4];
#pragma unroll
      for (int m = 0; m < 4; ++m) {
        int ar = wr * 64 + m * 16 + (lane & 15);
        int slot = kk * 4 + (lane >> 4);
        af[m] = *(const f16x8*)(Ab + ar * 128 + ((slot ^ (ar & 7)) * 16));
      }
#pragma unroll
      for (int n = 0; n < 4; ++n) {
        int br = wc * 64 + n * 16 + (lane & 15);
        int slot = kk * 4 + (lane >> 4);
        bfr[n] = *(const f16x8*)(Bb + br * 128 + ((slot ^ (br & 7)) * 16));
      }
#pragma unroll
      for (int m = 0; m < 4; ++m)
#pragma unroll
        for (int n = 0; n < 4; ++n)
          acc[m][n] = __builtin_amdgcn_mfma_f32_16x16x32_f16(af[m], bfr[n], acc[m][n], 0, 0, 0);
    }
    __builtin_amdgcn_sched_barrier(0);
    __builtin_amdgcn_s_barrier();
  }

  // epilogue: bias + gelu -> restage f16 C-tile in LDS -> coalesced stores
  float bias[4];
#pragma unroll
  for (int n = 0; n < 4; ++n)
    bias[n] = b1[(size_t)e * HDIM + n0 + wc * 64 + n * 16 + (lane & 15)];
#pragma unroll
  for (int m = 0; m < 4; ++m) {
#pragma unroll
    for (int j = 0; j < 4; ++j) {
      int row = wr * 64 + m * 16 + (lane >> 4) * 4 + j;
#pragma unroll
      for (int n = 0; n < 4; ++n) {
        int col = wc * 64 + n * 16 + (lane & 15);
        *(_Float16*)(smem + (row << 8) + (((col << 1) ^ ((row & 15) << 4)))) =
            (_Float16)gelu_tanh(acc[m][n][j] + bias[n]);
      }
    }
  }
  __syncthreads();
  {
    const int srow = tid >> 1, half = tid & 1;
    if (srow < mrem) {
      _Float16* hr = hbuf + (size_t)(off0 + m0 + srow) * HDIM + n0 + half * 64;
#pragma unroll
      for (int i = 0; i < 8; ++i) {
        f16x8 v = *(const f16x8*)(smem + (srow << 8) + (((half * 128 + i * 16) ^ ((srow & 15) << 4))));
        *(f16x8*)(hr + i * 8) = v;
      }
    }
  }
}

// ---------------- GEMM2: y = H @ w2t^T  (YB: f16 ybuf, else atomic+bias+weight) ----------------
template <bool YB>
__global__ __launch_bounds__(256) void k_gemm2(
    const _Float16* __restrict__ hbuf,  // [NPAIR][HDIM]
    const _Float16* __restrict__ w2t,   // [NEXP][DDIM][HDIM]
    const float* __restrict__ b2,       // [NEXP][DDIM]
    const int* __restrict__ offs,
    const int* __restrict__ row_token,
    const float* __restrict__ row_w,
    _Float16* __restrict__ yb,          // [NPAIR][DDIM] (YB path)
    float* __restrict__ out) {          // [TOK][DDIM]   (atomic path)
  const int e    = blockIdx.z;
  const int off0 = offs[e];
  const int ne   = offs[e + 1] - off0;
  const int m0   = blockIdx.y * BM;
  if (m0 >= ne) return;
  const int n0   = blockIdx.x * BN;
  const int mrem = ne - m0;

  __shared__ __align__(16) char smem[65536];

  const int tid = threadIdx.x;
  const int wv = tid >> 6, lane = tid & 63;
  const int sl = lane & 7, rsub = lane >> 3;
  const unsigned swzoff = (unsigned)((sl ^ rsub) * 16);

  const char* a_c = (const char*)hbuf;
  const char* b_c = (const char*)(w2t + (size_t)e * DDIM * HDIM);

  size_t abase[4], bbase[4];
#pragma unroll
  for (int i = 0; i < 4; ++i) {
    int r  = wv * 32 + i * 8 + rsub;
    int rr = (r < mrem) ? r : (mrem - 1);
    abase[i] = (size_t)(off0 + m0 + rr) * (HDIM * 2);
    bbase[i] = (size_t)(n0 + r) * (HDIM * 2);
  }

  f32x4 acc[4][4] = {};
  const int wr = wv >> 1, wc = wv & 1;
  const int NT = HDIM / BKK;   // 64

#pragma unroll
  for (int i = 0; i < 4; ++i) {
    gload16(a_c + abase[i] + swzoff, smem + (wv * 4 + i) * 1024);
    gload16(b_c + bbase[i] + swzoff, smem + 32768 + (wv * 4 + i) * 1024);
  }

  for (int ks = 0; ks < NT; ++ks) {
    const int cur = ks & 1;
    if (ks + 1 < NT) {
      const int nxt = cur ^ 1;
      const size_t kb = (size_t)(ks + 1) * (BKK * 2);
#pragma unroll
      for (int i = 0; i < 4; ++i) {
        gload16(a_c + abase[i] + kb + swzoff, smem + nxt * 16384 + (wv * 4 + i) * 1024);
        gload16(b_c + bbase[i] + kb + swzoff, smem + 32768 + nxt * 16384 + (wv * 4 + i) * 1024);
      }
      asm volatile("s_waitcnt vmcnt(8)" ::: "memory");
    } else {
      asm volatile("s_waitcnt vmcnt(0)" ::: "memory");
    }
    __builtin_amdgcn_sched_barrier(0);
    __builtin_amdgcn_s_barrier();
    const char* Ab = smem + cur * 16384;
    const char* Bb = smem + 32768 + cur * 16384;
#pragma unroll
    for (int kk = 0; kk < 2; ++kk) {
      f16x8 af[4], bfr[4];
#pragma unroll
      for (int m = 0; m < 4; ++m) {
        int ar = wr * 64 + m * 16 + (lane & 15);
        int slot = kk * 4 + (lane >> 4);
        af[m] = *(const f16x8*)(Ab + ar * 128 + ((slot ^ (ar & 7)) * 16));
      }
#pragma unroll
      for (int n = 0; n < 4; ++n) {
        int br = wc * 64 + n * 16 + (lane & 15);
        int slot = kk * 4 + (lane >> 4);
        bfr[n] = *(const f16x8*)(Bb + br * 128 + ((slot ^ (br & 7)) * 16));
      }
#pragma unroll
      for (int m = 0; m < 4; ++m)
#pragma unroll
        for (int n = 0; n < 4; ++n)
          acc[m][n] = __builtin_amdgcn_mfma_f32_16x16x32_f16(af[m], bfr[n], acc[m][n], 0, 0, 0);
    }
    __builtin_amdgcn_sched_barrier(0);
    __builtin_amdgcn_s_barrier();
  }

  if (YB) {
    // raw acc -> f16, restage in LDS, coalesced stores to ybuf (bias+weight in combine)
#pragma unroll
    for (int m = 0; m < 4; ++m) {
#pragma unroll
      for (int j = 0; j < 4; ++j) {
        int row = wr * 64 + m * 16 + (lane >> 4) * 4 + j;
#pragma unroll
        for (int n = 0; n < 4; ++n) {
          int col = wc * 64 + n * 16 + (lane & 15);
          *(_Float16*)(smem + (row << 8) + (((col << 1) ^ ((row & 15) << 4)))) =
              (_Float16)acc[m][n][j];
        }
      }
    }
    __syncthreads();
    const int srow = tid >> 1, half = tid & 1;
    if (srow < mrem) {
      _Float16* yr = yb + (size_t)(off0 + m0 + srow) * DDIM + n0 + half * 64;
#pragma unroll
      for (int i = 0; i < 8; ++i) {
        f16x8 v = *(const f16x8*)(smem + (srow << 8) + (((half * 128 + i * 16) ^ ((srow & 15) << 4))));
        *(f16x8*)(yr + i * 8) = v;
      }
    }
  } else {
    float bias[4];
#pragma unroll
    for (int n = 0; n < 4; ++n)
      bias[n] = b2[(size_t)e * DDIM + n0 + wc * 64 + n * 16 + (lane & 15)];
#pragma unroll
    for (int m = 0; m < 4; ++m) {
#pragma unroll
      for (int j = 0; j < 4; ++j) {
        int row = wr * 64 + m * 16 + (lane >> 4) * 4 + j;
        if (row < mrem) {
          int g = off0 + m0 + row;
          float wgt = row_w[g];
          float* op = out + (size_t)row_token[g] * DDIM + n0 + wc * 64 + (lane & 15);
#pragma unroll
          for (int n = 0; n < 4; ++n)
            atomicAdd(op + n * 16, wgt * (acc[m][n][j] + bias[n]));
        }
      }
    }
  }
}

// ---------------- combine: out[t] = sum_k tw[t,k] * (y[inv[t,k]] + b2[e_k]) ----------------
__global__ __launch_bounds__(256) void k_combine(const _Float16* __restrict__ yb,
    const int* __restrict__ inv, const int* __restrict__ tidx,
    const float* __restrict__ tw, const float* __restrict__ b2,
    float* __restrict__ out) {
  const int t  = blockIdx.x * 2 + (threadIdx.x >> 7);
  const int c8 = (threadIdx.x & 127) * 8;
  const int g0 = inv[2 * t],  g1 = inv[2 * t + 1];
  const int e0 = tidx[2 * t], e1 = tidx[2 * t + 1];
  const float w0 = tw[2 * t], w1 = tw[2 * t + 1];
  f16x8 y0 = *(const f16x8*)(yb + (size_t)g0 * DDIM + c8);
  f16x8 y1 = *(const f16x8*)(yb + (size_t)g1 * DDIM + c8);
  float o[8];
#pragma unroll
  for (int i = 0; i < 8; ++i) {
    float bA = b2[(size_t)e0 * DDIM + c8 + i];
    float bB = b2[(size_t)e1 * DDIM + c8 + i];
    o[i] = w0 * ((float)y0[i] + bA) + w1 * ((float)y1[i] + bB);
  }
  float* op = out + (size_t)t * DDIM + c8;
  *(float4*)op       = make_float4(o[0], o[1], o[2], o[3]);
  *(float4*)(op + 4) = make_float4(o[4], o[5], o[6], o[7]);
}

// ---------------- host ----------------
extern "C" void kernel_launch(void* const* d_in, const int* in_sizes, int n_in,
                              void* d_out, int out_size, void* d_ws, size_t ws_size,
                              hipStream_t stream) {
  const float* x  = (const float*)d_in[0];
  const float* rw = (const float*)d_in[1];
  const float* rb = (const float*)d_in[2];
  const float* w1 = (const float*)d_in[3];
  const float* b1 = (const float*)d_in[4];
  const float* w2 = (const float*)d_in[5];
  const float* b2 = (const float*)d_in[6];
  float* out = (float*)d_out;
  char* ws = (char*)d_ws;

  int*      tidx    = (int*)(ws + 0);               // 32KB
  float*    tw      = (float*)(ws + 32768);         // 32KB
  int*      counts  = (int*)(ws + 65536);
  int*      offs    = (int*)(ws + 65792);
  int*      row_tok = (int*)(ws + 66048);           // 32KB
  float*    row_w   = (float*)(ws + 98816);         // 32KB
  int*      inv     = (int*)(ws + 131584);          // 32KB
  _Float16* xb      = (_Float16*)(ws + 164352);     // 8MB
  _Float16* wt      = (_Float16*)(ws + 8552960);    // 64MB (w1t then w2t)
  _Float16* hb      = (_Float16*)(ws + 75661824);   // 64MB
  _Float16* yb      = (_Float16*)(ws + 142770688);  // 64MB
  const bool big = ws_size >= 209879552ULL;

  hipMemsetAsync(counts, 0, NEXP * sizeof(int), stream);
  if (!big) hipMemsetAsync(out, 0, (size_t)TOK * DDIM * sizeof(float), stream);

  k_router<<<dim3(TOK / 4), 256, 0, stream>>>(x, rw, rb, tidx, tw, counts);
  k_scan<<<dim3(1), 1024, 0, stream>>>(tidx, tw, counts, offs, row_tok, row_w, inv);
  k_cvt_x<<<dim3(TOK * DDIM / (256 * 8)), 256, 0, stream>>>(x, xb);
  k_transpose<<<dim3(HDIM / 64, DDIM / 64, NEXP), 256, 0, stream>>>(w1, wt, DDIM, HDIM);
  k_gemm1<<<dim3(HDIM / BN, TOK / BM, NEXP), 256, 0, stream>>>(xb, wt, b1, offs, row_tok, hb);
  k_transpose<<<dim3(DDIM / 64, HDIM / 64, NEXP), 256, 0, stream>>>(w2, wt, HDIM, DDIM);
  if (big) {
    k_gemm2<true><<<dim3(DDIM / BN, TOK / BM, NEXP), 256, 0, stream>>>(
        hb, wt, b2, offs, row_tok, row_w, yb, out);
    k_combine<<<dim3(TOK / 2), 256, 0, stream>>>(yb, inv, tidx, tw, b2, out);
  } else {
    k_gemm2<false><<<dim3(DDIM / BN, TOK / BM, NEXP), 256, 0, stream>>>(
        hb, wt, b2, offs, row_tok, row_w, yb, out);
  }
}

// Round 4
// 427.301 us; speedup vs baseline: 1.1975x; 1.0234x over previous
//
#include <hip/hip_runtime.h>
#include <hip/hip_bf16.h>

#define TOK   4096            // B*S
#define DDIM  1024
#define NEXP  8
#define HDIM  4096
#define KSEL  2
#define NPAIR (TOK * KSEL)    // 8192

typedef __attribute__((ext_vector_type(8))) _Float16 f16x8;
typedef __attribute__((ext_vector_type(4))) _Float16 f16x4;
typedef __attribute__((ext_vector_type(4))) float    f32x4;

__device__ __forceinline__ void gload16(const void* g, void* l) {
  __builtin_amdgcn_global_load_lds((const __attribute__((address_space(1))) void*)g,
                                   (__attribute__((address_space(3))) void*)l, 16, 0, 0);
}

__device__ __forceinline__ float gelu_tanh(float u) {
  float inner = 0.7978845608028654f * (u + 0.044715f * u * u * u);
  float t2 = __expf(2.f * inner);
  return u - u / (t2 + 1.f);     // == 0.5*u*(1+tanh(inner)), overflow-safe
}

// ---------------- router (+ fused x->fp16): one wave per token ----------------
__global__ __launch_bounds__(256) void k_router(const float* __restrict__ x,
    const float* __restrict__ rw, const float* __restrict__ rb,
    int* __restrict__ tidx, float* __restrict__ tw, int* __restrict__ counts,
    _Float16* __restrict__ xb) {
  const int t    = blockIdx.x * 4 + (threadIdx.x >> 6);
  const int lane = threadIdx.x & 63;
  const float* xr = x + (size_t)t * DDIM;
  _Float16*   xbr = xb + (size_t)t * DDIM;
  float acc[NEXP];
#pragma unroll
  for (int e = 0; e < NEXP; ++e) acc[e] = 0.f;
  for (int d0 = lane * 4; d0 < DDIM; d0 += 256) {
    const float4 xv = *(const float4*)(xr + d0);
    f16x4 hx;
    hx[0] = (_Float16)xv.x; hx[1] = (_Float16)xv.y;
    hx[2] = (_Float16)xv.z; hx[3] = (_Float16)xv.w;
    *(f16x4*)(xbr + d0) = hx;
#pragma unroll
    for (int i = 0; i < 4; ++i) {
      const float xs = (&xv.x)[i];
      const float4 r0 = *(const float4*)(rw + (size_t)(d0 + i) * NEXP);
      const float4 r1 = *(const float4*)(rw + (size_t)(d0 + i) * NEXP + 4);
      acc[0] += xs * r0.x; acc[1] += xs * r0.y; acc[2] += xs * r0.z; acc[3] += xs * r0.w;
      acc[4] += xs * r1.x; acc[5] += xs * r1.y; acc[6] += xs * r1.z; acc[7] += xs * r1.w;
    }
  }
#pragma unroll
  for (int e = 0; e < NEXP; ++e) {
    float v = acc[e];
#pragma unroll
    for (int s = 32; s; s >>= 1) v += __shfl_xor(v, s, 64);
    acc[e] = v;
  }
  if (lane == 0) {
    float lg[NEXP];
#pragma unroll
    for (int e = 0; e < NEXP; ++e) lg[e] = acc[e] + rb[e];
    int i0 = 0;
#pragma unroll
    for (int e = 1; e < NEXP; ++e) if (lg[e] > lg[i0]) i0 = e;
    int i1 = -1; float best = -3.4e38f;
#pragma unroll
    for (int e = 0; e < NEXP; ++e) {
      if (e == i0) continue;
      if (lg[e] > best) { best = lg[e]; i1 = e; }
    }
    float w0 = 1.f / (1.f + expf(lg[i1] - lg[i0]));
    tidx[t * 2]     = i0;  tidx[t * 2 + 1] = i1;
    tw[t * 2]       = w0;  tw[t * 2 + 1]   = 1.f - w0;
    atomicAdd(&counts[i0], 1);
    atomicAdd(&counts[i1], 1);
  }
}

// ---------------- scan + scatter (single block, ballot-aggregated) ----------------
__global__ __launch_bounds__(1024) void k_scan(const int* __restrict__ tidx,
                       const float* __restrict__ tw,
                       const int* __restrict__ counts, int* __restrict__ offs,
                       int* __restrict__ row_token, float* __restrict__ row_w,
                       int* __restrict__ inv) {
  __shared__ int soff[NEXP + 1];
  __shared__ int scur[NEXP];
  if (threadIdx.x == 0) {
    int run = 0;
    for (int e = 0; e < NEXP; ++e) { soff[e] = run; run += counts[e]; }
    soff[NEXP] = run;
    for (int e = 0; e <= NEXP; ++e) offs[e] = soff[e];
  }
  __syncthreads();
  if (threadIdx.x < NEXP) scur[threadIdx.x] = soff[threadIdx.x];
  __syncthreads();
  const int lane = threadIdx.x & 63;
#pragma unroll
  for (int it = 0; it < NPAIR / 1024; ++it) {
    const int p = it * 1024 + threadIdx.x;
    const int e = tidx[p];
    int pos = 0;
#pragma unroll
    for (int ee = 0; ee < NEXP; ++ee) {
      unsigned long long m = __ballot(e == ee);
      if (!m) continue;
      int base = 0;
      if (lane == 0) base = atomicAdd(&scur[ee], __popcll(m));
      base = __shfl(base, 0, 64);
      if (e == ee) pos = base + __popcll(m & ((1ull << lane) - 1ull));
    }
    row_token[pos] = p >> 1;
    row_w[pos]     = tw[p];
    inv[p]         = pos;
  }
}

// ---------------- transpose fp32 [Rr][Cc] -> fp16 [Cc][Rr], per expert ----------------
__global__ __launch_bounds__(256) void k_transpose(const float* __restrict__ in,
    _Float16* __restrict__ out, int Rr, int Cc) {
  __shared__ _Float16 tile[64][72];
  const size_t esz = (size_t)Rr * Cc;
  const float* ip = in + esz * blockIdx.z;
  _Float16*    op = out + esz * blockIdx.z;
  const int i0 = blockIdx.y * 64;
  const int j0 = blockIdx.x * 64;
  const int tx = threadIdx.x & 15, ty = threadIdx.x >> 4;
#pragma unroll
  for (int rr = 0; rr < 4; ++rr) {
    int r = ty + rr * 16;
    float4 v = *(const float4*)(ip + (size_t)(i0 + r) * Cc + j0 + tx * 4);
    tile[r][tx * 4 + 0] = (_Float16)v.x;
    tile[r][tx * 4 + 1] = (_Float16)v.y;
    tile[r][tx * 4 + 2] = (_Float16)v.z;
    tile[r][tx * 4 + 3] = (_Float16)v.w;
  }
  __syncthreads();
#pragma unroll
  for (int cc = 0; cc < 4; ++cc) {
    int c = ty + cc * 16;
    f16x4 o;
#pragma unroll
    for (int k = 0; k < 4; ++k) o[k] = tile[tx * 4 + k][c];
    *(f16x4*)(op + (size_t)(j0 + c) * Rr + i0 + tx * 4) = o;
  }
}

#define BM 128
#define BN 128
#define BKK 32

// LDS layout: A0[8K] A1[8K] B0[8K] B1[8K] = 32KB.
// A/B tile rows are 64B (32 halfs = 4 slots of 16B); physical slot = logical ^ ((row>>1)&3).

// ---------------- GEMM1: h = gelu(X_gathered @ w1t^T + b1), fp16 out ----------------
__global__ __launch_bounds__(256) void k_gemm1(
    const _Float16* __restrict__ xb,    // [TOK][DDIM]
    const _Float16* __restrict__ w1t,   // [NEXP][HDIM][DDIM]
    const float* __restrict__ b1,       // [NEXP][HDIM]
    const int* __restrict__ offs,
    const int* __restrict__ row_token,
    _Float16* __restrict__ hbuf) {      // [NPAIR][HDIM]
  const int e    = blockIdx.z;
  const int off0 = offs[e];
  const int ne   = offs[e + 1] - off0;
  const int m0   = blockIdx.y * BM;
  if (m0 >= ne) return;
  const int n0   = blockIdx.x * BN;
  const int mrem = ne - m0;

  __shared__ __align__(16) char smem[32768];

  const int tid = threadIdx.x;
  const int wv = tid >> 6, lane = tid & 63;
  const int l15 = lane & 15;
  const int wr = wv >> 1, wc = wv & 1;

  // staging geometry: chunk c = wv*2+i covers rows c*16..c*16+15; 4 lanes/row (slots 0-3)
  const int rA0 = (wv * 2 + 0) * 16 + (lane >> 2);
  const int rA1 = (wv * 2 + 1) * 16 + (lane >> 2);
  const char* a_c = (const char*)xb;
  const char* b_c = (const char*)(w1t + (size_t)e * HDIM * DDIM);
  const int rc0 = (rA0 < mrem) ? rA0 : (mrem - 1);
  const int rc1 = (rA1 < mrem) ? rA1 : (mrem - 1);
  const char* ap0 = a_c + (size_t)row_token[off0 + m0 + rc0] * (DDIM * 2)
                        + (((lane & 3) ^ ((rA0 >> 1) & 3)) << 4);
  const char* ap1 = a_c + (size_t)row_token[off0 + m0 + rc1] * (DDIM * 2)
                        + (((lane & 3) ^ ((rA1 >> 1) & 3)) << 4);
  const char* bp0 = b_c + (size_t)(n0 + rA0) * (DDIM * 2)
                        + (((lane & 3) ^ ((rA0 >> 1) & 3)) << 4);
  const char* bp1 = b_c + (size_t)(n0 + rA1) * (DDIM * 2)
                        + (((lane & 3) ^ ((rA1 >> 1) & 3)) << 4);
  char* ldsA0 = smem + (wv * 2 + 0) * 1024;
  char* ldsA1 = smem + (wv * 2 + 1) * 1024;
  char* ldsB0 = smem + 16384 + (wv * 2 + 0) * 1024;
  char* ldsB1 = smem + 16384 + (wv * 2 + 1) * 1024;

  const unsigned foff = (unsigned)(((lane >> 4) ^ ((l15 >> 1) & 3)) << 4);

  f32x4 acc[4][4] = {};
  const int NT = DDIM / BKK;   // 32

  // prologue: stage tile 0 into buffer 0
  gload16(ap0, ldsA0); gload16(ap1, ldsA1);
  gload16(bp0, ldsB0); gload16(bp1, ldsB1);

#pragma unroll 2
  for (int ks = 0; ks < NT; ++ks) {
    const int cur = ks & 1;
    if (ks + 1 < NT) {
      const int nb = (cur ^ 1) * 8192;
      const size_t kb = (size_t)(ks + 1) * 64;
      gload16(ap0 + kb, ldsA0 + nb); gload16(ap1 + kb, ldsA1 + nb);
      gload16(bp0 + kb, ldsB0 + nb); gload16(bp1 + kb, ldsB1 + nb);
      asm volatile("s_waitcnt vmcnt(4)" ::: "memory");
    } else {
      asm volatile("s_waitcnt vmcnt(0)" ::: "memory");
    }
    __builtin_amdgcn_sched_barrier(0);
    __builtin_amdgcn_s_barrier();
    const char* Ab = smem + cur * 8192;
    const char* Bb = smem + 16384 + cur * 8192;
    f16x8 af[4], bfr[4];
#pragma unroll
    for (int m = 0; m < 4; ++m)
      af[m] = *(const f16x8*)(Ab + (wr * 64 + m * 16 + l15) * 64 + foff);
#pragma unroll
    for (int n = 0; n < 4; ++n)
      bfr[n] = *(const f16x8*)(Bb + (wc * 64 + n * 16 + l15) * 64 + foff);
#pragma unroll
    for (int m = 0; m < 4; ++m)
#pragma unroll
      for (int n = 0; n < 4; ++n)
        acc[m][n] = __builtin_amdgcn_mfma_f32_16x16x32_f16(af[m], bfr[n], acc[m][n], 0, 0, 0);
    __builtin_amdgcn_sched_barrier(0);
    __builtin_amdgcn_s_barrier();
  }

  // epilogue: bias + gelu -> restage f16 C-tile in LDS -> coalesced stores
  float bias[4];
#pragma unroll
  for (int n = 0; n < 4; ++n)
    bias[n] = b1[(size_t)e * HDIM + n0 + wc * 64 + n * 16 + l15];
#pragma unroll
  for (int m = 0; m < 4; ++m) {
#pragma unroll
    for (int j = 0; j < 4; ++j) {
      int row = wr * 64 + m * 16 + (lane >> 4) * 4 + j;
#pragma unroll
      for (int n = 0; n < 4; ++n) {
        int col = wc * 64 + n * 16 + l15;
        *(_Float16*)(smem + (row << 8) + (((col << 1) ^ ((row & 15) << 4)))) =
            (_Float16)gelu_tanh(acc[m][n][j] + bias[n]);
      }
    }
  }
  __syncthreads();
  {
    const int srow = tid >> 1, half = tid & 1;
    if (srow < mrem) {
      _Float16* hr = hbuf + (size_t)(off0 + m0 + srow) * HDIM + n0 + half * 64;
#pragma unroll
      for (int i = 0; i < 8; ++i) {
        f16x8 v = *(const f16x8*)(smem + (srow << 8) + (((half * 128 + i * 16) ^ ((srow & 15) << 4))));
        *(f16x8*)(hr + i * 8) = v;
      }
    }
  }
}

// ---------------- GEMM2 (split-K=2): ypart[kh] = H @ w2t^T ----------------
template <bool YB>
__global__ __launch_bounds__(256) void k_gemm2(
    const _Float16* __restrict__ hbuf,  // [NPAIR][HDIM]
    const _Float16* __restrict__ w2t,   // [NEXP][DDIM][HDIM]
    const float* __restrict__ b2,       // [NEXP][DDIM]
    const int* __restrict__ offs,
    const int* __restrict__ row_token,
    const float* __restrict__ row_w,
    _Float16* __restrict__ yb,          // [2][NPAIR][DDIM] partials (YB path)
    float* __restrict__ out) {          // [TOK][DDIM]      (atomic path)
  const int e    = blockIdx.z >> 1;
  const int kh   = blockIdx.z & 1;
  const int off0 = offs[e];
  const int ne   = offs[e + 1] - off0;
  const int m0   = blockIdx.y * BM;
  if (m0 >= ne) return;
  const int n0   = blockIdx.x * BN;
  const int mrem = ne - m0;

  __shared__ __align__(16) char smem[32768];

  const int tid = threadIdx.x;
  const int wv = tid >> 6, lane = tid & 63;
  const int l15 = lane & 15;
  const int wr = wv >> 1, wc = wv & 1;

  const int rA0 = (wv * 2 + 0) * 16 + (lane >> 2);
  const int rA1 = (wv * 2 + 1) * 16 + (lane >> 2);
  const char* a_c = (const char*)hbuf;
  const char* b_c = (const char*)(w2t + (size_t)e * DDIM * HDIM);
  const int rc0 = (rA0 < mrem) ? rA0 : (mrem - 1);
  const int rc1 = (rA1 < mrem) ? rA1 : (mrem - 1);
  const size_t khb = (size_t)kh * (2048 * 2);   // byte offset of K-half
  const char* ap0 = a_c + (size_t)(off0 + m0 + rc0) * (HDIM * 2) + khb
                        + (((lane & 3) ^ ((rA0 >> 1) & 3)) << 4);
  const char* ap1 = a_c + (size_t)(off0 + m0 + rc1) * (HDIM * 2) + khb
                        + (((lane & 3) ^ ((rA1 >> 1) & 3)) << 4);
  const char* bp0 = b_c + (size_t)(n0 + rA0) * (HDIM * 2) + khb
                        + (((lane & 3) ^ ((rA0 >> 1) & 3)) << 4);
  const char* bp1 = b_c + (size_t)(n0 + rA1) * (HDIM * 2) + khb
                        + (((lane & 3) ^ ((rA1 >> 1) & 3)) << 4);
  char* ldsA0 = smem + (wv * 2 + 0) * 1024;
  char* ldsA1 = smem + (wv * 2 + 1) * 1024;
  char* ldsB0 = smem + 16384 + (wv * 2 + 0) * 1024;
  char* ldsB1 = smem + 16384 + (wv * 2 + 1) * 1024;

  const unsigned foff = (unsigned)(((lane >> 4) ^ ((l15 >> 1) & 3)) << 4);

  f32x4 acc[4][4] = {};
  const int NT = 2048 / BKK;   // 64

  gload16(ap0, ldsA0); gload16(ap1, ldsA1);
  gload16(bp0, ldsB0); gload16(bp1, ldsB1);

#pragma unroll 2
  for (int ks = 0; ks < NT; ++ks) {
    const int cur = ks & 1;
    if (ks + 1 < NT) {
      const int nb = (cur ^ 1) * 8192;
      const size_t kb = (size_t)(ks + 1) * 64;
      gload16(ap0 + kb, ldsA0 + nb); gload16(ap1 + kb, ldsA1 + nb);
      gload16(bp0 + kb, ldsB0 + nb); gload16(bp1 + kb, ldsB1 + nb);
      asm volatile("s_waitcnt vmcnt(4)" ::: "memory");
    } else {
      asm volatile("s_waitcnt vmcnt(0)" ::: "memory");
    }
    __builtin_amdgcn_sched_barrier(0);
    __builtin_amdgcn_s_barrier();
    const char* Ab = smem + cur * 8192;
    const char* Bb = smem + 16384 + cur * 8192;
    f16x8 af[4], bfr[4];
#pragma unroll
    for (int m = 0; m < 4; ++m)
      af[m] = *(const f16x8*)(Ab + (wr * 64 + m * 16 + l15) * 64 + foff);
#pragma unroll
    for (int n = 0; n < 4; ++n)
      bfr[n] = *(const f16x8*)(Bb + (wc * 64 + n * 16 + l15) * 64 + foff);
#pragma unroll
    for (int m = 0; m < 4; ++m)
#pragma unroll
      for (int n = 0; n < 4; ++n)
        acc[m][n] = __builtin_amdgcn_mfma_f32_16x16x32_f16(af[m], bfr[n], acc[m][n], 0, 0, 0);
    __builtin_amdgcn_sched_barrier(0);
    __builtin_amdgcn_s_barrier();
  }

  if (YB) {
    _Float16* ypart = yb + (size_t)kh * NPAIR * DDIM;
#pragma unroll
    for (int m = 0; m < 4; ++m) {
#pragma unroll
      for (int j = 0; j < 4; ++j) {
        int row = wr * 64 + m * 16 + (lane >> 4) * 4 + j;
#pragma unroll
        for (int n = 0; n < 4; ++n) {
          int col = wc * 64 + n * 16 + l15;
          *(_Float16*)(smem + (row << 8) + (((col << 1) ^ ((row & 15) << 4)))) =
              (_Float16)acc[m][n][j];
        }
      }
    }
    __syncthreads();
    const int srow = tid >> 1, half = tid & 1;
    if (srow < mrem) {
      _Float16* yr = ypart + (size_t)(off0 + m0 + srow) * DDIM + n0 + half * 64;
#pragma unroll
      for (int i = 0; i < 8; ++i) {
        f16x8 v = *(const f16x8*)(smem + (srow << 8) + (((half * 128 + i * 16) ^ ((srow & 15) << 4))));
        *(f16x8*)(yr + i * 8) = v;
      }
    }
  } else {
    float bias[4];
#pragma unroll
    for (int n = 0; n < 4; ++n)
      bias[n] = (kh == 0) ? b2[(size_t)e * DDIM + n0 + wc * 64 + n * 16 + l15] : 0.f;
#pragma unroll
    for (int m = 0; m < 4; ++m) {
#pragma unroll
      for (int j = 0; j < 4; ++j) {
        int row = wr * 64 + m * 16 + (lane >> 4) * 4 + j;
        if (row < mrem) {
          int g = off0 + m0 + row;
          float wgt = row_w[g];
          float* op = out + (size_t)row_token[g] * DDIM + n0 + wc * 64 + l15;
#pragma unroll
          for (int n = 0; n < 4; ++n)
            atomicAdd(op + n * 16, wgt * (acc[m][n][j] + bias[n]));
        }
      }
    }
  }
}

// ---------------- combine: out[t] = sum_k tw[t,k] * (y0[g]+y1[g] + b2[e_k]) ----------------
__global__ __launch_bounds__(256) void k_combine(const _Float16* __restrict__ yb,
    const int* __restrict__ inv, const int* __restrict__ tidx,
    const float* __restrict__ tw, const float* __restrict__ b2,
    float* __restrict__ out) {
  const int t  = blockIdx.x * 2 + (threadIdx.x >> 7);
  const int c8 = (threadIdx.x & 127) * 8;
  const int g0 = inv[2 * t],  g1 = inv[2 * t + 1];
  const int e0 = tidx[2 * t], e1 = tidx[2 * t + 1];
  const float w0 = tw[2 * t], w1 = tw[2 * t + 1];
  const _Float16* y1p = yb + (size_t)NPAIR * DDIM;
  f16x8 a0 = *(const f16x8*)(yb  + (size_t)g0 * DDIM + c8);
  f16x8 a1 = *(const f16x8*)(y1p + (size_t)g0 * DDIM + c8);
  f16x8 b0 = *(const f16x8*)(yb  + (size_t)g1 * DDIM + c8);
  f16x8 b1v = *(const f16x8*)(y1p + (size_t)g1 * DDIM + c8);
  float o[8];
#pragma unroll
  for (int i = 0; i < 8; ++i) {
    float bA = b2[(size_t)e0 * DDIM + c8 + i];
    float bB = b2[(size_t)e1 * DDIM + c8 + i];
    o[i] = w0 * ((float)a0[i] + (float)a1[i] + bA) + w1 * ((float)b0[i] + (float)b1v[i] + bB);
  }
  float* op = out + (size_t)t * DDIM + c8;
  *(float4*)op       = make_float4(o[0], o[1], o[2], o[3]);
  *(float4*)(op + 4) = make_float4(o[4], o[5], o[6], o[7]);
}

// ---------------- host ----------------
extern "C" void kernel_launch(void* const* d_in, const int* in_sizes, int n_in,
                              void* d_out, int out_size, void* d_ws, size_t ws_size,
                              hipStream_t stream) {
  const float* x  = (const float*)d_in[0];
  const float* rw = (const float*)d_in[1];
  const float* rb = (const float*)d_in[2];
  const float* w1 = (const float*)d_in[3];
  const float* b1 = (const float*)d_in[4];
  const float* w2 = (const float*)d_in[5];
  const float* b2 = (const float*)d_in[6];
  float* out = (float*)d_out;
  char* ws = (char*)d_ws;

  int*      tidx    = (int*)(ws + 0);               // 32KB
  float*    tw      = (float*)(ws + 32768);         // 32KB
  int*      counts  = (int*)(ws + 65536);
  int*      offs    = (int*)(ws + 65792);
  int*      row_tok = (int*)(ws + 66048);           // 32KB
  float*    row_w   = (float*)(ws + 98816);         // 32KB
  int*      inv     = (int*)(ws + 131584);          // 32KB
  _Float16* xb      = (_Float16*)(ws + 164352);     // 8MB
  _Float16* wt      = (_Float16*)(ws + 8552960);    // 64MB (w1t then w2t)
  _Float16* hb      = (_Float16*)(ws + 75661824);   // 64MB
  _Float16* yb      = (_Float16*)(ws + 142770688);  // 32MB (2 x 16MB partials)
  const bool big = ws_size >= 209879552ULL;

  hipMemsetAsync(counts, 0, NEXP * sizeof(int), stream);
  if (!big) hipMemsetAsync(out, 0, (size_t)TOK * DDIM * sizeof(float), stream);

  k_router<<<dim3(TOK / 4), 256, 0, stream>>>(x, rw, rb, tidx, tw, counts, xb);
  k_scan<<<dim3(1), 1024, 0, stream>>>(tidx, tw, counts, offs, row_tok, row_w, inv);
  k_transpose<<<dim3(HDIM / 64, DDIM / 64, NEXP), 256, 0, stream>>>(w1, wt, DDIM, HDIM);
  k_gemm1<<<dim3(HDIM / BN, TOK / BM, NEXP), 256, 0, stream>>>(xb, wt, b1, offs, row_tok, hb);
  k_transpose<<<dim3(DDIM / 64, HDIM / 64, NEXP), 256, 0, stream>>>(w2, wt, HDIM, DDIM);
  if (big) {
    k_gemm2<true><<<dim3(DDIM / BN, TOK / BM, NEXP * 2), 256, 0, stream>>>(
        hb, wt, b2, offs, row_tok, row_w, yb, out);
    k_combine<<<dim3(TOK / 2), 256, 0, stream>>>(yb, inv, tidx, tw, b2, out);
  } else {
    k_gemm2<false><<<dim3(DDIM / BN, TOK / BM, NEXP * 2), 256, 0, stream>>>(
        hb, wt, b2, offs, row_tok, row_w, yb, out);
  }
}